// Round 1
// baseline (315.529 us; speedup 1.0000x reference)
//
#include <hip/hip_runtime.h>

#define NB 64
#define LC 1024
#define LQ 128
#define DD 128
#define NEG_BIG 1.0e12f

__device__ __forceinline__ float wave_reduce_max(float v) {
#pragma unroll
  for (int m = 32; m >= 1; m >>= 1) v = fmaxf(v, __shfl_xor(v, m, 64));
  return v;
}
__device__ __forceinline__ float wave_reduce_sum(float v) {
#pragma unroll
  for (int m = 32; m >= 1; m >>= 1) v += __shfl_xor(v, m, 64);
  return v;
}

// ---------------------------------------------------------------------------
// K0: out[row] = dot(x[row, 0:128], w[0:128])   (one wave per row)
// ---------------------------------------------------------------------------
__global__ __launch_bounds__(256) void k_rowdot(const float* __restrict__ x,
                                                const float* __restrict__ w,
                                                float* __restrict__ out, int nrows) {
  const int lane = threadIdx.x & 63;
  const int row = (blockIdx.x << 2) + (threadIdx.x >> 6);
  if (row >= nrows) return;
  const float2 v = *(const float2*)(x + (size_t)row * DD + (lane << 1));
  const float2 wv = *(const float2*)(w + (lane << 1));
  float s = fmaf(v.x, wv.x, v.y * wv.y);
  s = wave_reduce_sum(s);
  if (lane == 0) out[row] = s;
}

// ---------------------------------------------------------------------------
// K1: per (b, 64-row c-tile):
//   S[c,q] = a_cont[c] + a_ques[q] + sum_d xc[c,d]*W2[d]*xq[q,d]
//   - q-masked softmax over q -> out_sbar[b,c,q]
//   - raw S transposed       -> out_st[b,q,c]
// block = 256 threads (4 waves); wave handles 16 rows; lane holds q=lane, q=lane+64
// ---------------------------------------------------------------------------
__global__ __launch_bounds__(256) void k_score(
    const float* __restrict__ xc, const float* __restrict__ xq,
    const float* __restrict__ w2, const float* __restrict__ a_cont,
    const float* __restrict__ a_ques, const int* __restrict__ qlen_p,
    float* __restrict__ out_sbar, float* __restrict__ out_st) {
  __shared__ float xq_s[64 * 128];    // one q-half, W2-folded, chunk-XOR-swizzled (32KB)
  __shared__ float s_tile[32 * 129];  // raw-S transpose staging, padded (16.5KB)

  const int b = blockIdx.x >> 4;
  const int c0 = (blockIdx.x & 15) << 6;
  const int t = threadIdx.x;
  const int w = t >> 6, lane = t & 63;
  const int qlen = qlen_p[b];
  const float aq0 = a_ques[b * LQ + lane];
  const float aq1 = a_ques[b * LQ + 64 + lane];

  const float* xq_b = xq + (size_t)b * LQ * DD;
  const float* xc_blk = xc + ((size_t)b * LC + c0) * DD;
  const int rbase = w * 16;

  float v[16][2];
#pragma unroll
  for (int r = 0; r < 16; ++r) { v[r][0] = 0.f; v[r][1] = 0.f; }

#pragma unroll
  for (int h = 0; h < 2; ++h) {
    __syncthreads();
    // stage q-half h: 64 q rows x 128 d, fold W2, XOR-swizzle 4-dword chunks
#pragma unroll
    for (int i = 0; i < 8; ++i) {
      const int id = t + (i << 8);  // 0..2047 float4 units
      const int qr = id >> 5;
      const int cd = id & 31;
      const float4 xv = *(const float4*)(xq_b + (size_t)((h << 6) + qr) * DD + (cd << 2));
      const float4 wv = *(const float4*)(w2 + (cd << 2));
      *(float4*)(xq_s + qr * 128 + (((cd ^ (qr & 7)) << 2))) =
          make_float4(xv.x * wv.x, xv.y * wv.y, xv.z * wv.z, xv.w * wv.w);
    }
    __syncthreads();
    for (int cd = 0; cd < 32; ++cd) {
      const float4 xqv = *(const float4*)(xq_s + lane * 128 + ((cd ^ (lane & 7)) << 2));
#pragma unroll
      for (int r = 0; r < 16; ++r) {
        const float4 xcv = *(const float4*)(xc_blk + (size_t)(rbase + r) * DD + (cd << 2));
        v[r][h] = fmaf(xcv.x, xqv.x, v[r][h]);
        v[r][h] = fmaf(xcv.y, xqv.y, v[r][h]);
        v[r][h] = fmaf(xcv.z, xqv.z, v[r][h]);
        v[r][h] = fmaf(xcv.w, xqv.w, v[r][h]);
      }
    }
  }

  // per-row q-softmax; keep raw scores in v[][]
  const float* ac_p = a_cont + b * LC + c0 + rbase;
  float* sbar_blk = out_sbar + ((size_t)b * LC + (c0 + rbase)) * LQ;
#pragma unroll
  for (int r = 0; r < 16; ++r) {
    const float ac = ac_p[r];
    const float raw0 = v[r][0] + ac + aq0;
    const float raw1 = v[r][1] + ac + aq1;
    v[r][0] = raw0;
    v[r][1] = raw1;
    const float x0 = (lane < qlen) ? raw0 : raw0 - NEG_BIG;
    const float x1 = (64 + lane < qlen) ? raw1 : raw1 - NEG_BIG;
    const float m = wave_reduce_max(fmaxf(x0, x1));
    const float e0 = __expf(x0 - m);
    const float e1 = __expf(x1 - m);
    const float s = wave_reduce_sum(e0 + e1);
    const float inv = 1.0f / s;
    sbar_blk[r * LQ + lane] = e0 * inv;
    sbar_blk[r * LQ + 64 + lane] = e1 * inv;
  }

  // transposed write of raw S in two 32-row phases (LDS budget)
  float* st_blk = out_st + (size_t)b * LQ * LC;
#pragma unroll
  for (int ph = 0; ph < 2; ++ph) {
    __syncthreads();
    if ((w >> 1) == ph) {
      const int rl = (w & 1) * 16;
#pragma unroll
      for (int r = 0; r < 16; ++r) {
        s_tile[(rl + r) * 129 + lane] = v[r][0];
        s_tile[(rl + r) * 129 + 64 + lane] = v[r][1];
      }
    }
    __syncthreads();
    const int cl = lane & 31;
    const int qo = lane >> 5;
    const int cg = c0 + (ph << 5) + cl;
#pragma unroll
    for (int qi = 0; qi < 16; ++qi) {
      const int q = (w << 5) + (qi << 1) + qo;
      st_blk[(size_t)q * LC + cg] = s_tile[cl * 129 + q];
    }
  }
}

// ---------------------------------------------------------------------------
// K2: in-place c-masked softmax over each 1024-long row of out_st[b,q,:]
// ---------------------------------------------------------------------------
__global__ __launch_bounds__(256) void k_colsoftmax(float* __restrict__ st,
                                                    const int* __restrict__ clen_p) {
  __shared__ float red[8];
  const int bq = blockIdx.x;
  const int b = bq >> 7;
  const int L = clen_p[b];
  float* row = st + (size_t)bq * LC;
  const int t = threadIdx.x;
  const int w = t >> 6, lane = t & 63;
  const int c = t << 2;
  const float4 vv = *(const float4*)(row + c);
  const float m0 = (c + 0 < L) ? vv.x : vv.x - NEG_BIG;
  const float m1 = (c + 1 < L) ? vv.y : vv.y - NEG_BIG;
  const float m2 = (c + 2 < L) ? vv.z : vv.z - NEG_BIG;
  const float m3 = (c + 3 < L) ? vv.w : vv.w - NEG_BIG;
  float m = fmaxf(fmaxf(m0, m1), fmaxf(m2, m3));
  m = wave_reduce_max(m);
  if (lane == 0) red[w] = m;
  __syncthreads();
  m = fmaxf(fmaxf(red[0], red[1]), fmaxf(red[2], red[3]));
  const float e0 = __expf(m0 - m), e1 = __expf(m1 - m);
  const float e2 = __expf(m2 - m), e3 = __expf(m3 - m);
  float s = wave_reduce_sum(e0 + e1 + e2 + e3);
  if (lane == 0) red[4 + w] = s;
  __syncthreads();
  s = (red[4] + red[5]) + (red[6] + red[7]);
  const float inv = 1.0f / s;
  *(float4*)(row + c) = make_float4(e0 * inv, e1 * inv, e2 * inv, e3 * inv);
}

// ---------------------------------------------------------------------------
// K3: A[b,q,d] = sum_c S_T[b,q,c] * xc[b,c,d]   (block = (b, 32-q tile))
// ---------------------------------------------------------------------------
__global__ __launch_bounds__(256) void k_aq(const float* __restrict__ st,
                                            const float* __restrict__ xc,
                                            float* __restrict__ A) {
  __shared__ float xcs[64 * 128];  // 32KB: 64-c chunk of xc
  __shared__ float wsm[32 * 64];   // 8KB: S_T weights 32q x 64c
  const int b = blockIdx.x >> 2;
  const int q0 = (blockIdx.x & 3) << 5;
  const int t = threadIdx.x;
  const int w = t >> 6, lane = t & 63;
  const float* xc_b = xc + (size_t)b * LC * DD;
  const float* st_b = st + ((size_t)b * LQ + q0) * LC;

  float acc[8][2];
#pragma unroll
  for (int i = 0; i < 8; ++i) { acc[i][0] = 0.f; acc[i][1] = 0.f; }

  for (int cc = 0; cc < 16; ++cc) {
    __syncthreads();
#pragma unroll
    for (int i = 0; i < 8; ++i) {
      const int id = t + (i << 8);  // 2048 float4 units
      const int r = id >> 5, cd = id & 31;
      *(float4*)(xcs + r * 128 + (cd << 2)) =
          *(const float4*)(xc_b + (size_t)(cc * 64 + r) * DD + (cd << 2));
    }
#pragma unroll
    for (int i = 0; i < 2; ++i) {
      const int id = t + (i << 8);  // 512 float4 units
      const int qi = id >> 4, cd = id & 15;
      *(float4*)(wsm + qi * 64 + (cd << 2)) =
          *(const float4*)(st_b + (size_t)qi * LC + cc * 64 + (cd << 2));
    }
    __syncthreads();
#pragma unroll 2
    for (int c = 0; c < 64; ++c) {
      const float2 xv = *(const float2*)(xcs + c * 128 + (lane << 1));
#pragma unroll
      for (int i = 0; i < 8; ++i) {
        const float wv = wsm[(w * 8 + i) * 64 + c];
        acc[i][0] = fmaf(wv, xv.x, acc[i][0]);
        acc[i][1] = fmaf(wv, xv.y, acc[i][1]);
      }
    }
  }
#pragma unroll
  for (int i = 0; i < 8; ++i) {
    const int q = q0 + w * 8 + i;
    *(float2*)(A + ((size_t)b * LQ + q) * DD + (lane << 1)) =
        make_float2(acc[i][0], acc[i][1]);
  }
}

// ---------------------------------------------------------------------------
// K4: c2q = S_bar@xq, q2c = S_bar@A, fused concat epilogue
//     out[b,c,:] = [xc | c2q | xc*c2q | xc*q2c]   (block = (b, 32-c tile))
// ---------------------------------------------------------------------------
__global__ __launch_bounds__(256) void k_out(const float* __restrict__ xc,
                                             const float* __restrict__ xq,
                                             const float* __restrict__ sbar,
                                             const float* __restrict__ A,
                                             float* __restrict__ out) {
  __shared__ float xqs[32 * 128];  // 16KB
  __shared__ float As[32 * 128];   // 16KB
  __shared__ float sbs[32 * 32];   // 4KB
  const int b = blockIdx.x >> 5;
  const int c0 = (blockIdx.x & 31) << 5;
  const int t = threadIdx.x;
  const int w = t >> 6, lane = t & 63;
  const float* xq_b = xq + (size_t)b * LQ * DD;
  const float* A_b = A + (size_t)b * LQ * DD;
  const float* sb_blk = sbar + ((size_t)b * LC + c0) * LQ;

  float c2q[8][2], q2c[8][2];
#pragma unroll
  for (int i = 0; i < 8; ++i) {
    c2q[i][0] = 0.f; c2q[i][1] = 0.f;
    q2c[i][0] = 0.f; q2c[i][1] = 0.f;
  }

  for (int qc = 0; qc < 4; ++qc) {
    __syncthreads();
#pragma unroll
    for (int i = 0; i < 4; ++i) {
      const int id = t + (i << 8);  // 1024 float4 units
      const int r = id >> 5, cd = id & 31;
      *(float4*)(xqs + r * 128 + (cd << 2)) =
          *(const float4*)(xq_b + (size_t)(qc * 32 + r) * DD + (cd << 2));
      *(float4*)(As + r * 128 + (cd << 2)) =
          *(const float4*)(A_b + (size_t)(qc * 32 + r) * DD + (cd << 2));
    }
    {
      const int ci = t >> 3, qj = t & 7;  // 256 float4 units
      *(float4*)(sbs + ci * 32 + (qj << 2)) =
          *(const float4*)(sb_blk + (size_t)ci * LQ + qc * 32 + (qj << 2));
    }
    __syncthreads();
#pragma unroll 2
    for (int qj = 0; qj < 32; ++qj) {
      const float2 xv = *(const float2*)(xqs + qj * 128 + (lane << 1));
      const float2 av = *(const float2*)(As + qj * 128 + (lane << 1));
#pragma unroll
      for (int i = 0; i < 8; ++i) {
        const float wv = sbs[(w * 8 + i) * 32 + qj];
        c2q[i][0] = fmaf(wv, xv.x, c2q[i][0]);
        c2q[i][1] = fmaf(wv, xv.y, c2q[i][1]);
        q2c[i][0] = fmaf(wv, av.x, q2c[i][0]);
        q2c[i][1] = fmaf(wv, av.y, q2c[i][1]);
      }
    }
  }

#pragma unroll
  for (int i = 0; i < 8; ++i) {
    const int c = c0 + w * 8 + i;
    const float2 xv = *(const float2*)(xc + ((size_t)b * LC + c) * DD + (lane << 1));
    float* o = out + ((size_t)b * LC + c) * (4 * DD);
    const int d2 = lane << 1;
    *(float2*)(o + d2) = xv;
    *(float2*)(o + DD + d2) = make_float2(c2q[i][0], c2q[i][1]);
    *(float2*)(o + 2 * DD + d2) = make_float2(xv.x * c2q[i][0], xv.y * c2q[i][1]);
    *(float2*)(o + 3 * DD + d2) = make_float2(xv.x * q2c[i][0], xv.y * q2c[i][1]);
  }
}

extern "C" void kernel_launch(void* const* d_in, const int* in_sizes, int n_in,
                              void* d_out, int out_size, void* d_ws, size_t ws_size,
                              hipStream_t stream) {
  const float* xc = (const float*)d_in[0];
  const float* xq = (const float*)d_in[1];
  const float* W0 = (const float*)d_in[2];
  const float* W1 = (const float*)d_in[3];
  const float* W2 = (const float*)d_in[4];
  const int* clen = (const int*)d_in[5];
  const int* qlen = (const int*)d_in[6];

  float* out = (float*)d_out;
  float* out_sbar = out + (size_t)NB * LC * 4 * DD;  // result is (B,LC,4D)
  float* out_st = out_sbar + (size_t)NB * LC * LQ;   // S_bar is (B,LC,LQ)

  float* a_cont = (float*)d_ws;           // NB*LC floats
  float* a_ques = a_cont + NB * LC;       // NB*LQ floats
  float* A = a_ques + NB * LQ;            // NB*LQ*DD floats

  k_rowdot<<<(NB * LC) / 4, 256, 0, stream>>>(xc, W0, a_cont, NB * LC);
  k_rowdot<<<(NB * LQ) / 4, 256, 0, stream>>>(xq, W1, a_ques, NB * LQ);
  k_score<<<NB * 16, 256, 0, stream>>>(xc, xq, W2, a_cont, a_ques, qlen,
                                       out_sbar, out_st);
  k_colsoftmax<<<NB * LQ, 256, 0, stream>>>(out_st, clen);
  k_aq<<<NB * 4, 256, 0, stream>>>(out_st, xc, A);
  k_out<<<NB * 32, 256, 0, stream>>>(xc, xq, out_sbar, A, out);
}

// Round 2
// 183.219 us; speedup vs baseline: 1.7221x; 1.7221x over previous
//
#include <hip/hip_runtime.h>

#define NB 64
#define LC 1024
#define LQ 128
#define DD 128
#define NEG_BIG 1.0e12f

typedef __attribute__((ext_vector_type(8))) short short8;
typedef __attribute__((ext_vector_type(4))) float floatx4;

__device__ __forceinline__ float wave_reduce_max(float v) {
#pragma unroll
  for (int m = 32; m >= 1; m >>= 1) v = fmaxf(v, __shfl_xor(v, m, 64));
  return v;
}
__device__ __forceinline__ float wave_reduce_sum(float v) {
#pragma unroll
  for (int m = 32; m >= 1; m >>= 1) v += __shfl_xor(v, m, 64);
  return v;
}

__device__ __forceinline__ unsigned short f2bf(float f) {
  union { float f; unsigned int u; } v;
  v.f = f;
  const unsigned int r = v.u + 0x7FFFu + ((v.u >> 16) & 1u);
  return (unsigned short)(r >> 16);
}

// ---------------------------------------------------------------------------
// K0: out[row] = dot(x[row, 0:128], w[0:128])   (one wave per row)
// ---------------------------------------------------------------------------
__global__ __launch_bounds__(256) void k_rowdot(const float* __restrict__ x,
                                                const float* __restrict__ w,
                                                float* __restrict__ out, int nrows) {
  const int lane = threadIdx.x & 63;
  const int row = (blockIdx.x << 2) + (threadIdx.x >> 6);
  if (row >= nrows) return;
  const float2 v = *(const float2*)(x + (size_t)row * DD + (lane << 1));
  const float2 wv = *(const float2*)(w + (lane << 1));
  float s = fmaf(v.x, wv.x, v.y * wv.y);
  s = wave_reduce_sum(s);
  if (lane == 0) out[row] = s;
}

// ---------------------------------------------------------------------------
// K1 (MFMA): per (b, 128-row c-tile):
//   S[c,q] = a_cont[c] + a_ques[q] + sum_d xc[c,d]*W2[d]*xq[q,d]
//   - q-masked softmax over q -> out_sbar[b,c,q]
//   - raw S transposed        -> out_st[b,q,c]
// block = 512 threads (8 waves); wave w computes c-rows [w*16, w*16+16) x 128 q
// via mfma_f32_16x16x32_bf16 (8 n-tiles x 4 k-steps).
// ---------------------------------------------------------------------------
#define PADW 136  // LDS row stride in bf16 elems (+4 banks/row -> <=2-way)

__global__ __launch_bounds__(512) void k_score(
    const float* __restrict__ xc, const float* __restrict__ xq,
    const float* __restrict__ w2, const float* __restrict__ a_cont,
    const float* __restrict__ a_ques, const int* __restrict__ qlen_p,
    float* __restrict__ out_sbar, float* __restrict__ out_st) {
  __shared__ __align__(16) unsigned short smem[2 * 128 * PADW];  // 69632 B
  unsigned short* xcs = smem;                 // 128 x PADW bf16 (c-tile)
  unsigned short* xqs = smem + 128 * PADW;    // 128 x PADW bf16 (xq * W2)
  float* s_tile = (float*)smem;               // [32][132] f32, aliases xcs (dead)

  const int b = blockIdx.x >> 3;
  const int c0 = (blockIdx.x & 7) << 7;
  const int t = threadIdx.x;
  const int w = t >> 6, lane = t & 63;
  const int frow = lane & 15;  // A-row / B-col within 16
  const int kb = lane >> 4;    // k-group (8 wide)

  const float* xc_blk = xc + ((size_t)b * LC + c0) * DD;
  const float* xq_b = xq + (size_t)b * LQ * DD;

  // ---- stage xc-tile and xq*W2 as bf16 into LDS (8 floats per unit) ----
#pragma unroll
  for (int i = 0; i < 4; ++i) {
    const int id = t + (i << 9);  // 0..2047
    const int row = id >> 4, u = id & 15;
    {
      const float4 v0 = *(const float4*)(xc_blk + (size_t)row * DD + (u << 3));
      const float4 v1 = *(const float4*)(xc_blk + (size_t)row * DD + (u << 3) + 4);
      short8 pk;
      pk[0] = (short)f2bf(v0.x); pk[1] = (short)f2bf(v0.y);
      pk[2] = (short)f2bf(v0.z); pk[3] = (short)f2bf(v0.w);
      pk[4] = (short)f2bf(v1.x); pk[5] = (short)f2bf(v1.y);
      pk[6] = (short)f2bf(v1.z); pk[7] = (short)f2bf(v1.w);
      *(short8*)(xcs + row * PADW + (u << 3)) = pk;
    }
    {
      const float4 v0 = *(const float4*)(xq_b + (size_t)row * DD + (u << 3));
      const float4 v1 = *(const float4*)(xq_b + (size_t)row * DD + (u << 3) + 4);
      const float4 w0 = *(const float4*)(w2 + (u << 3));
      const float4 w1 = *(const float4*)(w2 + (u << 3) + 4);
      short8 pk;
      pk[0] = (short)f2bf(v0.x * w0.x); pk[1] = (short)f2bf(v0.y * w0.y);
      pk[2] = (short)f2bf(v0.z * w0.z); pk[3] = (short)f2bf(v0.w * w0.w);
      pk[4] = (short)f2bf(v1.x * w1.x); pk[5] = (short)f2bf(v1.y * w1.y);
      pk[6] = (short)f2bf(v1.z * w1.z); pk[7] = (short)f2bf(v1.w * w1.w);
      *(short8*)(xqs + row * PADW + (u << 3)) = pk;
    }
  }

  // preload bias terms + qlen (hide latency under MFMA)
  const int qlen = qlen_p[b];
  float ac[4], aq[8];
#pragma unroll
  for (int reg = 0; reg < 4; ++reg)
    ac[reg] = a_cont[b * LC + c0 + w * 16 + kb * 4 + reg];
#pragma unroll
  for (int n = 0; n < 8; ++n) aq[n] = a_ques[b * LQ + n * 16 + frow];

  __syncthreads();

  // ---- MFMA: wave computes 16c x 128q ----
  floatx4 acc[8];
#pragma unroll
  for (int n = 0; n < 8; ++n) acc[n] = (floatx4){0.f, 0.f, 0.f, 0.f};
  const unsigned short* arow = xcs + (w * 16 + frow) * PADW + kb * 8;
  const unsigned short* brow = xqs + frow * PADW + kb * 8;
#pragma unroll
  for (int ks = 0; ks < 4; ++ks) {
    const short8 af = *(const short8*)(arow + ks * 32);
#pragma unroll
    for (int n = 0; n < 8; ++n) {
      const short8 bf = *(const short8*)(brow + n * 16 * PADW + ks * 32);
      acc[n] = __builtin_amdgcn_mfma_f32_16x16x32_bf16(af, bf, acc[n], 0, 0, 0);
    }
  }

  // ---- raw scores; q-masked softmax (in-register) -> S_bar ----
  float raw[8][4];
#pragma unroll
  for (int n = 0; n < 8; ++n)
#pragma unroll
    for (int reg = 0; reg < 4; ++reg) raw[n][reg] = acc[n][reg] + ac[reg] + aq[n];

  float* sbar_row0 =
      out_sbar + ((size_t)b * LC + c0 + w * 16 + kb * 4) * LQ + frow;
#pragma unroll
  for (int reg = 0; reg < 4; ++reg) {
    float x[8];
    float m = -3.4e38f;
#pragma unroll
    for (int n = 0; n < 8; ++n) {
      x[n] = raw[n][reg] - ((n * 16 + frow) < qlen ? 0.f : NEG_BIG);
      m = fmaxf(m, x[n]);
    }
#pragma unroll
    for (int msk = 8; msk >= 1; msk >>= 1) m = fmaxf(m, __shfl_xor(m, msk, 64));
    float s = 0.f;
#pragma unroll
    for (int n = 0; n < 8; ++n) {
      x[n] = __expf(x[n] - m);
      s += x[n];
    }
#pragma unroll
    for (int msk = 8; msk >= 1; msk >>= 1) s += __shfl_xor(s, msk, 64);
    const float inv = 1.0f / s;
    float* o = sbar_row0 + (size_t)reg * LQ;
#pragma unroll
    for (int n = 0; n < 8; ++n) o[n * 16] = x[n] * inv;
  }

  // ---- transposed raw-S write via LDS (4 phases of 32 q-rows) ----
  float* st_b = out_st + (size_t)b * LQ * LC;
#pragma unroll
  for (int p = 0; p < 4; ++p) {
    __syncthreads();
#pragma unroll
    for (int n2 = 0; n2 < 2; ++n2) {
#pragma unroll
      for (int reg = 0; reg < 4; ++reg)
        s_tile[(n2 * 16 + frow) * 132 + (w * 16 + kb * 4 + reg)] =
            raw[2 * p + n2][reg];
    }
    __syncthreads();
    const int qrow = t >> 4;   // 0..31
    const int cch = t & 15;    // chunks cch, cch+16 of 32
    const float4 u0 = *(const float4*)(s_tile + qrow * 132 + (cch << 2));
    const float4 u1 = *(const float4*)(s_tile + qrow * 132 + ((cch + 16) << 2));
    float* dst = st_b + (size_t)(p * 32 + qrow) * LC + c0;
    *(float4*)(dst + (cch << 2)) = u0;
    *(float4*)(dst + ((cch + 16) << 2)) = u1;
  }
}

// ---------------------------------------------------------------------------
// K2: in-place c-masked softmax over each 1024-long row of out_st[b,q,:]
// ---------------------------------------------------------------------------
__global__ __launch_bounds__(256) void k_colsoftmax(float* __restrict__ st,
                                                    const int* __restrict__ clen_p) {
  __shared__ float red[8];
  const int bq = blockIdx.x;
  const int b = bq >> 7;
  const int L = clen_p[b];
  float* row = st + (size_t)bq * LC;
  const int t = threadIdx.x;
  const int w = t >> 6, lane = t & 63;
  const int c = t << 2;
  const float4 vv = *(const float4*)(row + c);
  const float m0 = (c + 0 < L) ? vv.x : vv.x - NEG_BIG;
  const float m1 = (c + 1 < L) ? vv.y : vv.y - NEG_BIG;
  const float m2 = (c + 2 < L) ? vv.z : vv.z - NEG_BIG;
  const float m3 = (c + 3 < L) ? vv.w : vv.w - NEG_BIG;
  float m = fmaxf(fmaxf(m0, m1), fmaxf(m2, m3));
  m = wave_reduce_max(m);
  if (lane == 0) red[w] = m;
  __syncthreads();
  m = fmaxf(fmaxf(red[0], red[1]), fmaxf(red[2], red[3]));
  const float e0 = __expf(m0 - m), e1 = __expf(m1 - m);
  const float e2 = __expf(m2 - m), e3 = __expf(m3 - m);
  float s = wave_reduce_sum(e0 + e1 + e2 + e3);
  if (lane == 0) red[4 + w] = s;
  __syncthreads();
  s = (red[4] + red[5]) + (red[6] + red[7]);
  const float inv = 1.0f / s;
  *(float4*)(row + c) = make_float4(e0 * inv, e1 * inv, e2 * inv, e3 * inv);
}

// ---------------------------------------------------------------------------
// K3: A[b,q,d] = sum_c S_T[b,q,c] * xc[b,c,d]   (block = (b, 32-q tile))
// ---------------------------------------------------------------------------
__global__ __launch_bounds__(256) void k_aq(const float* __restrict__ st,
                                            const float* __restrict__ xc,
                                            float* __restrict__ A) {
  __shared__ float xcs[64 * 128];  // 32KB: 64-c chunk of xc
  __shared__ float wsm[32 * 64];   // 8KB: S_T weights 32q x 64c
  const int b = blockIdx.x >> 2;
  const int q0 = (blockIdx.x & 3) << 5;
  const int t = threadIdx.x;
  const int w = t >> 6, lane = t & 63;
  const float* xc_b = xc + (size_t)b * LC * DD;
  const float* st_b = st + ((size_t)b * LQ + q0) * LC;

  float acc[8][2];
#pragma unroll
  for (int i = 0; i < 8; ++i) { acc[i][0] = 0.f; acc[i][1] = 0.f; }

  for (int cc = 0; cc < 16; ++cc) {
    __syncthreads();
#pragma unroll
    for (int i = 0; i < 8; ++i) {
      const int id = t + (i << 8);  // 2048 float4 units
      const int r = id >> 5, cd = id & 31;
      *(float4*)(xcs + r * 128 + (cd << 2)) =
          *(const float4*)(xc_b + (size_t)(cc * 64 + r) * DD + (cd << 2));
    }
#pragma unroll
    for (int i = 0; i < 2; ++i) {
      const int id = t + (i << 8);  // 512 float4 units
      const int qi = id >> 4, cd = id & 15;
      *(float4*)(wsm + qi * 64 + (cd << 2)) =
          *(const float4*)(st_b + (size_t)qi * LC + cc * 64 + (cd << 2));
    }
    __syncthreads();
#pragma unroll 2
    for (int c = 0; c < 64; ++c) {
      const float2 xv = *(const float2*)(xcs + c * 128 + (lane << 1));
#pragma unroll
      for (int i = 0; i < 8; ++i) {
        const float wv = wsm[(w * 8 + i) * 64 + c];
        acc[i][0] = fmaf(wv, xv.x, acc[i][0]);
        acc[i][1] = fmaf(wv, xv.y, acc[i][1]);
      }
    }
  }
#pragma unroll
  for (int i = 0; i < 8; ++i) {
    const int q = q0 + w * 8 + i;
    *(float2*)(A + ((size_t)b * LQ + q) * DD + (lane << 1)) =
        make_float2(acc[i][0], acc[i][1]);
  }
}

// ---------------------------------------------------------------------------
// K4: c2q = S_bar@xq, q2c = S_bar@A, fused concat epilogue
//     out[b,c,:] = [xc | c2q | xc*c2q | xc*q2c]   (block = (b, 32-c tile))
// ---------------------------------------------------------------------------
__global__ __launch_bounds__(256) void k_out(const float* __restrict__ xc,
                                             const float* __restrict__ xq,
                                             const float* __restrict__ sbar,
                                             const float* __restrict__ A,
                                             float* __restrict__ out) {
  __shared__ float xqs[32 * 128];  // 16KB
  __shared__ float As[32 * 128];   // 16KB
  __shared__ float sbs[32 * 32];   // 4KB
  const int b = blockIdx.x >> 5;
  const int c0 = (blockIdx.x & 31) << 5;
  const int t = threadIdx.x;
  const int w = t >> 6, lane = t & 63;
  const float* xq_b = xq + (size_t)b * LQ * DD;
  const float* A_b = A + (size_t)b * LQ * DD;
  const float* sb_blk = sbar + ((size_t)b * LC + c0) * LQ;

  float c2q[8][2], q2c[8][2];
#pragma unroll
  for (int i = 0; i < 8; ++i) {
    c2q[i][0] = 0.f; c2q[i][1] = 0.f;
    q2c[i][0] = 0.f; q2c[i][1] = 0.f;
  }

  for (int qc = 0; qc < 4; ++qc) {
    __syncthreads();
#pragma unroll
    for (int i = 0; i < 4; ++i) {
      const int id = t + (i << 8);  // 1024 float4 units
      const int r = id >> 5, cd = id & 31;
      *(float4*)(xqs + r * 128 + (cd << 2)) =
          *(const float4*)(xq_b + (size_t)(qc * 32 + r) * DD + (cd << 2));
      *(float4*)(As + r * 128 + (cd << 2)) =
          *(const float4*)(A_b + (size_t)(qc * 32 + r) * DD + (cd << 2));
    }
    {
      const int ci = t >> 3, qj = t & 7;  // 256 float4 units
      *(float4*)(sbs + ci * 32 + (qj << 2)) =
          *(const float4*)(sb_blk + (size_t)ci * LQ + qc * 32 + (qj << 2));
    }
    __syncthreads();
#pragma unroll 2
    for (int qj = 0; qj < 32; ++qj) {
      const float2 xv = *(const float2*)(xqs + qj * 128 + (lane << 1));
      const float2 av = *(const float2*)(As + qj * 128 + (lane << 1));
#pragma unroll
      for (int i = 0; i < 8; ++i) {
        const float wv = sbs[(w * 8 + i) * 32 + qj];
        c2q[i][0] = fmaf(wv, xv.x, c2q[i][0]);
        c2q[i][1] = fmaf(wv, xv.y, c2q[i][1]);
        q2c[i][0] = fmaf(wv, av.x, q2c[i][0]);
        q2c[i][1] = fmaf(wv, av.y, q2c[i][1]);
      }
    }
  }

#pragma unroll
  for (int i = 0; i < 8; ++i) {
    const int c = c0 + w * 8 + i;
    const float2 xv = *(const float2*)(xc + ((size_t)b * LC + c) * DD + (lane << 1));
    float* o = out + ((size_t)b * LC + c) * (4 * DD);
    const int d2 = lane << 1;
    *(float2*)(o + d2) = xv;
    *(float2*)(o + DD + d2) = make_float2(c2q[i][0], c2q[i][1]);
    *(float2*)(o + 2 * DD + d2) = make_float2(xv.x * c2q[i][0], xv.y * c2q[i][1]);
    *(float2*)(o + 3 * DD + d2) = make_float2(xv.x * q2c[i][0], xv.y * q2c[i][1]);
  }
}

extern "C" void kernel_launch(void* const* d_in, const int* in_sizes, int n_in,
                              void* d_out, int out_size, void* d_ws, size_t ws_size,
                              hipStream_t stream) {
  const float* xc = (const float*)d_in[0];
  const float* xq = (const float*)d_in[1];
  const float* W0 = (const float*)d_in[2];
  const float* W1 = (const float*)d_in[3];
  const float* W2 = (const float*)d_in[4];
  const int* clen = (const int*)d_in[5];
  const int* qlen = (const int*)d_in[6];

  float* out = (float*)d_out;
  float* out_sbar = out + (size_t)NB * LC * 4 * DD;  // result is (B,LC,4D)
  float* out_st = out_sbar + (size_t)NB * LC * LQ;   // S_bar is (B,LC,LQ)

  float* a_cont = (float*)d_ws;           // NB*LC floats
  float* a_ques = a_cont + NB * LC;       // NB*LQ floats
  float* A = a_ques + NB * LQ;            // NB*LQ*DD floats

  k_rowdot<<<(NB * LC) / 4, 256, 0, stream>>>(xc, W0, a_cont, NB * LC);
  k_rowdot<<<(NB * LQ) / 4, 256, 0, stream>>>(xq, W1, a_ques, NB * LQ);
  k_score<<<NB * 8, 512, 0, stream>>>(xc, xq, W2, a_cont, a_ques, qlen,
                                      out_sbar, out_st);
  k_colsoftmax<<<NB * LQ, 256, 0, stream>>>(out_st, clen);
  k_aq<<<NB * 4, 256, 0, stream>>>(out_st, xc, A);
  k_out<<<NB * 32, 256, 0, stream>>>(xc, xq, out_sbar, A, out);
}

// Round 3
// 121.988 us; speedup vs baseline: 2.5866x; 1.5019x over previous
//
#include <hip/hip_runtime.h>

#define NB 64
#define LC 1024
#define LQ 128
#define DD 128
#define NEG_BIG 1.0e12f

typedef __attribute__((ext_vector_type(8))) short short8;
typedef __attribute__((ext_vector_type(4))) unsigned short ushort4v;
typedef __attribute__((ext_vector_type(4))) float floatx4;

__device__ __forceinline__ float wave_reduce_max(float v) {
#pragma unroll
  for (int m = 32; m >= 1; m >>= 1) v = fmaxf(v, __shfl_xor(v, m, 64));
  return v;
}
__device__ __forceinline__ float wave_reduce_sum(float v) {
#pragma unroll
  for (int m = 32; m >= 1; m >>= 1) v += __shfl_xor(v, m, 64);
  return v;
}
__device__ __forceinline__ unsigned short f2bf(float f) {
  union { float f; unsigned int u; } v;
  v.f = f;
  const unsigned int r = v.u + 0x7FFFu + ((v.u >> 16) & 1u);
  return (unsigned short)(r >> 16);
}
__device__ __forceinline__ float bf2f(unsigned int u) {
  union { unsigned int u; float f; } v;
  v.u = u << 16;
  return v.f;
}

// ---------------------------------------------------------------------------
// K_pre_c: per (b, 64-c tile): xc -> bf16 row-major (xcb) + bf16 transposed
// (xcT[b][d][c]) + a_cont = xc . W0
// ---------------------------------------------------------------------------
__global__ __launch_bounds__(256) void k_pre_c(
    const float* __restrict__ xc, const float* __restrict__ W0,
    unsigned short* __restrict__ xcb, unsigned short* __restrict__ xcT,
    float* __restrict__ a_cont) {
  __shared__ __align__(16) unsigned short tile[64 * 136];
  const int b = blockIdx.x >> 4;
  const int c0 = (blockIdx.x & 15) << 6;
  const int t = threadIdx.x;
  const int w = t >> 6, lane = t & 63;
  const float* src = xc + ((size_t)b * LC + c0) * DD;
  unsigned short* dstb = xcb + ((size_t)b * LC + c0) * DD;

#pragma unroll
  for (int i = 0; i < 8; ++i) {
    const int id = t + (i << 8);
    const int row = id >> 5, u = id & 31;
    const float4 v = *(const float4*)(src + (size_t)row * DD + (u << 2));
    ushort4v pk;
    pk[0] = f2bf(v.x); pk[1] = f2bf(v.y); pk[2] = f2bf(v.z); pk[3] = f2bf(v.w);
    *(ushort4v*)(tile + row * 136 + (u << 2)) = pk;
    *(ushort4v*)(dstb + (size_t)row * DD + (u << 2)) = pk;
  }
  const float w0a = W0[lane << 1];
  const float w0b = W0[(lane << 1) + 1];
  __syncthreads();
#pragma unroll
  for (int r = 0; r < 16; ++r) {
    const int row = (w << 4) + r;
    const unsigned int pk = *(const unsigned int*)(tile + row * 136 + (lane << 1));
    float s = fmaf(bf2f(pk & 0xffffu), w0a, bf2f(pk >> 16) * w0b);
    s = wave_reduce_sum(s);
    if (lane == 0) a_cont[b * LC + c0 + row] = s;
  }
  // transpose write: xcT[b][d][c0+ch*32 .. +32]
  const int d = t >> 1, ch = t & 1;
  short8 o[4];
#pragma unroll
  for (int j = 0; j < 32; ++j)
    ((unsigned short*)o)[j] = tile[(ch * 32 + j) * 136 + d];
  unsigned short* dp = xcT + ((size_t)b * DD + d) * LC + c0 + ch * 32;
#pragma unroll
  for (int j = 0; j < 4; ++j) *(short8*)(dp + (j << 3)) = o[j];
}

// ---------------------------------------------------------------------------
// K_pre_q: per b: xq*W2 -> bf16 row-major (xqwb), xq -> bf16 transposed
// (xqT[b][d][q]), a_ques = xq . W1
// ---------------------------------------------------------------------------
__global__ __launch_bounds__(256) void k_pre_q(
    const float* __restrict__ xq, const float* __restrict__ W1,
    const float* __restrict__ W2, unsigned short* __restrict__ xqwb,
    unsigned short* __restrict__ xqT, float* __restrict__ a_ques) {
  __shared__ __align__(16) unsigned short tile[128 * 136];
  const int b = blockIdx.x;
  const int t = threadIdx.x;
  const int w = t >> 6, lane = t & 63;
  const float* src = xq + (size_t)b * LQ * DD;
  unsigned short* dstw = xqwb + (size_t)b * LQ * DD;

#pragma unroll
  for (int i = 0; i < 16; ++i) {
    const int id = t + (i << 8);
    const int row = id >> 5, u = id & 31;
    const float4 v = *(const float4*)(src + (size_t)row * DD + (u << 2));
    const float4 wv = *(const float4*)(W2 + (u << 2));
    ushort4v pk, pf;
    pk[0] = f2bf(v.x); pk[1] = f2bf(v.y); pk[2] = f2bf(v.z); pk[3] = f2bf(v.w);
    pf[0] = f2bf(v.x * wv.x); pf[1] = f2bf(v.y * wv.y);
    pf[2] = f2bf(v.z * wv.z); pf[3] = f2bf(v.w * wv.w);
    *(ushort4v*)(tile + row * 136 + (u << 2)) = pk;
    *(ushort4v*)(dstw + (size_t)row * DD + (u << 2)) = pf;
  }
  const float w1a = W1[lane << 1];
  const float w1b = W1[(lane << 1) + 1];
  __syncthreads();
#pragma unroll
  for (int r = 0; r < 32; ++r) {
    const int row = (w << 5) + r;
    const unsigned int pk = *(const unsigned int*)(tile + row * 136 + (lane << 1));
    float s = fmaf(bf2f(pk & 0xffffu), w1a, bf2f(pk >> 16) * w1b);
    s = wave_reduce_sum(s);
    if (lane == 0) a_ques[b * LQ + row] = s;
  }
  // transpose: xqT[b][d][q]
  const int d = t >> 1, ch = t & 1;
  short8 o[8];
#pragma unroll
  for (int j = 0; j < 64; ++j)
    ((unsigned short*)o)[j] = tile[(ch * 64 + j) * 136 + d];
  unsigned short* dp = xqT + ((size_t)b * DD + d) * LQ + ch * 64;
#pragma unroll
  for (int j = 0; j < 8; ++j) *(short8*)(dp + (j << 3)) = o[j];
}

// ---------------------------------------------------------------------------
// K1 (MFMA): S = a_cont + a_ques + (xc.W2) xq^T; q-softmax -> sbar; raw S^T -> st
// ---------------------------------------------------------------------------
#define PADW 136

__global__ __launch_bounds__(512) void k_score(
    const unsigned short* __restrict__ xcb, const unsigned short* __restrict__ xqwb,
    const float* __restrict__ a_cont, const float* __restrict__ a_ques,
    const int* __restrict__ qlen_p, float* __restrict__ out_sbar,
    float* __restrict__ out_st) {
  __shared__ __align__(16) unsigned short smem[2 * 128 * PADW];  // 69632 B
  unsigned short* xcs = smem;
  unsigned short* xqs = smem + 128 * PADW;
  float* s_tile = (float*)smem;  // [32][132] f32, aliases xcs (dead after MFMA)

  const int b = blockIdx.x >> 3;
  const int c0 = (blockIdx.x & 7) << 7;
  const int t = threadIdx.x;
  const int w = t >> 6, lane = t & 63;
  const int frow = lane & 15;
  const int kb = lane >> 4;

  const unsigned short* xcb_blk = xcb + ((size_t)b * LC + c0) * DD;
  const unsigned short* xqw_b = xqwb + (size_t)b * LQ * DD;

#pragma unroll
  for (int i = 0; i < 4; ++i) {
    const int id = t + (i << 9);
    const int row = id >> 4, u = id & 15;
    *(short8*)(xcs + row * PADW + (u << 3)) =
        *(const short8*)(xcb_blk + (size_t)row * DD + (u << 3));
    *(short8*)(xqs + row * PADW + (u << 3)) =
        *(const short8*)(xqw_b + (size_t)row * DD + (u << 3));
  }

  const int qlen = qlen_p[b];
  float ac[4], aq[8];
#pragma unroll
  for (int reg = 0; reg < 4; ++reg)
    ac[reg] = a_cont[b * LC + c0 + w * 16 + kb * 4 + reg];
#pragma unroll
  for (int n = 0; n < 8; ++n) aq[n] = a_ques[b * LQ + n * 16 + frow];

  __syncthreads();

  floatx4 acc[8];
#pragma unroll
  for (int n = 0; n < 8; ++n) acc[n] = (floatx4){0.f, 0.f, 0.f, 0.f};
  const unsigned short* arow = xcs + (w * 16 + frow) * PADW + kb * 8;
  const unsigned short* brow = xqs + frow * PADW + kb * 8;
#pragma unroll
  for (int ks = 0; ks < 4; ++ks) {
    const short8 af = *(const short8*)(arow + ks * 32);
#pragma unroll
    for (int n = 0; n < 8; ++n) {
      const short8 bf = *(const short8*)(brow + n * 16 * PADW + ks * 32);
      acc[n] = __builtin_amdgcn_mfma_f32_16x16x32_bf16(af, bf, acc[n], 0, 0, 0);
    }
  }

  float raw[8][4];
#pragma unroll
  for (int n = 0; n < 8; ++n)
#pragma unroll
    for (int reg = 0; reg < 4; ++reg) raw[n][reg] = acc[n][reg] + ac[reg] + aq[n];

  float* sbar_row0 =
      out_sbar + ((size_t)b * LC + c0 + w * 16 + kb * 4) * LQ + frow;
#pragma unroll
  for (int reg = 0; reg < 4; ++reg) {
    float x[8];
    float m = -3.4e38f;
#pragma unroll
    for (int n = 0; n < 8; ++n) {
      x[n] = raw[n][reg] - ((n * 16 + frow) < qlen ? 0.f : NEG_BIG);
      m = fmaxf(m, x[n]);
    }
#pragma unroll
    for (int msk = 8; msk >= 1; msk >>= 1) m = fmaxf(m, __shfl_xor(m, msk, 64));
    float s = 0.f;
#pragma unroll
    for (int n = 0; n < 8; ++n) {
      x[n] = __expf(x[n] - m);
      s += x[n];
    }
#pragma unroll
    for (int msk = 8; msk >= 1; msk >>= 1) s += __shfl_xor(s, msk, 64);
    const float inv = 1.0f / s;
    float* o = sbar_row0 + (size_t)reg * LQ;
#pragma unroll
    for (int n = 0; n < 8; ++n) o[n * 16] = x[n] * inv;
  }

  float* st_b = out_st + (size_t)b * LQ * LC;
#pragma unroll
  for (int p = 0; p < 4; ++p) {
    __syncthreads();
#pragma unroll
    for (int n2 = 0; n2 < 2; ++n2) {
#pragma unroll
      for (int reg = 0; reg < 4; ++reg)
        s_tile[(n2 * 16 + frow) * 132 + (w * 16 + kb * 4 + reg)] =
            raw[2 * p + n2][reg];
    }
    __syncthreads();
    const int qrow = t >> 4;
    const int cch = t & 15;
    const float4 u0 = *(const float4*)(s_tile + qrow * 132 + (cch << 2));
    const float4 u1 = *(const float4*)(s_tile + qrow * 132 + ((cch + 16) << 2));
    float* dst = st_b + (size_t)(p * 32 + qrow) * LC + c0;
    *(float4*)(dst + (cch << 2)) = u0;
    *(float4*)(dst + ((cch + 16) << 2)) = u1;
  }
}

// ---------------------------------------------------------------------------
// K_fuse: per (b, 16-q tile): masked c-softmax of raw st rows (in-register),
// write normalized st (f32), keep unnormalized P bf16 in LDS, then
// MFMA A = P @ xc (K=1024 via xcT chunks), scale by 1/s, write AbT[b][d][q] bf16.
// ---------------------------------------------------------------------------
#define PSTR 1028

__global__ __launch_bounds__(256) void k_fuse(
    float* __restrict__ st, const unsigned short* __restrict__ xcT,
    const int* __restrict__ clen_p, unsigned short* __restrict__ AbT) {
  __shared__ __align__(16) unsigned short P[16 * PSTR];  // 32896 B
  __shared__ __align__(16) unsigned short bt[128 * 72];  // 18432 B
  __shared__ unsigned short abt[128 * 20];               // 5120 B
  __shared__ float inv_s[16];

  const int b = blockIdx.x >> 3;
  const int q0 = (blockIdx.x & 7) << 4;
  const int t = threadIdx.x;
  const int w = t >> 6, lane = t & 63;
  const int frow = lane & 15, kb = lane >> 4;
  const int L = clen_p[b];
  float* st_blk = st + ((size_t)b * LQ + q0) * LC;

  // softmax: wave w owns rows w*4 .. w*4+4
#pragma unroll
  for (int r = 0; r < 4; ++r) {
    const int row = (w << 2) + r;
    float* rowp = st_blk + (size_t)row * LC;
    float4 v[4];
    float m = -3.4e38f;
#pragma unroll
    for (int ph = 0; ph < 4; ++ph) {
      const int c = (lane << 2) + (ph << 8);
      v[ph] = *(const float4*)(rowp + c);
      if (c + 0 < L) m = fmaxf(m, v[ph].x);
      if (c + 1 < L) m = fmaxf(m, v[ph].y);
      if (c + 2 < L) m = fmaxf(m, v[ph].z);
      if (c + 3 < L) m = fmaxf(m, v[ph].w);
    }
    m = wave_reduce_max(m);
    float s = 0.f;
#pragma unroll
    for (int ph = 0; ph < 4; ++ph) {
      const int c = (lane << 2) + (ph << 8);
      v[ph].x = (c + 0 < L) ? __expf(v[ph].x - m) : 0.f;
      v[ph].y = (c + 1 < L) ? __expf(v[ph].y - m) : 0.f;
      v[ph].z = (c + 2 < L) ? __expf(v[ph].z - m) : 0.f;
      v[ph].w = (c + 3 < L) ? __expf(v[ph].w - m) : 0.f;
      s += (v[ph].x + v[ph].y) + (v[ph].z + v[ph].w);
      ushort4v pk;
      pk[0] = f2bf(v[ph].x); pk[1] = f2bf(v[ph].y);
      pk[2] = f2bf(v[ph].z); pk[3] = f2bf(v[ph].w);
      *(ushort4v*)(P + row * PSTR + c) = pk;
    }
    s = wave_reduce_sum(s);
    const float inv = 1.0f / s;
    if (lane == 0) inv_s[row] = inv;
#pragma unroll
    for (int ph = 0; ph < 4; ++ph) {
      const int c = (lane << 2) + (ph << 8);
      *(float4*)(rowp + c) =
          make_float4(v[ph].x * inv, v[ph].y * inv, v[ph].z * inv, v[ph].w * inv);
    }
  }

  // GEMM: A[q][d] = sum_c P[q][c] * xc[c][d]; B-operand = xcT[d][c]
  const unsigned short* xcT_b = xcT + (size_t)b * DD * LC;
  floatx4 acc0 = (floatx4){0.f, 0.f, 0.f, 0.f};
  floatx4 acc1 = (floatx4){0.f, 0.f, 0.f, 0.f};
  for (int kc = 0; kc < 16; ++kc) {
    __syncthreads();
#pragma unroll
    for (int i = 0; i < 4; ++i) {
      const int id = t + (i << 8);
      const int row = id >> 3, u = id & 7;
      *(short8*)(bt + row * 72 + (u << 3)) =
          *(const short8*)(xcT_b + (size_t)row * LC + (kc << 6) + (u << 3));
    }
    __syncthreads();
#pragma unroll
    for (int ks = 0; ks < 2; ++ks) {
      const short8 af =
          *(const short8*)(P + frow * PSTR + (kc << 6) + ks * 32 + kb * 8);
      const short8 b0 =
          *(const short8*)(bt + ((w * 2 + 0) * 16 + frow) * 72 + ks * 32 + kb * 8);
      const short8 b1 =
          *(const short8*)(bt + ((w * 2 + 1) * 16 + frow) * 72 + ks * 32 + kb * 8);
      acc0 = __builtin_amdgcn_mfma_f32_16x16x32_bf16(af, b0, acc0, 0, 0, 0);
      acc1 = __builtin_amdgcn_mfma_f32_16x16x32_bf16(af, b1, acc1, 0, 0, 0);
    }
  }
  __syncthreads();
  const float i0 = inv_s[kb * 4 + 0], i1 = inv_s[kb * 4 + 1];
  const float i2 = inv_s[kb * 4 + 2], i3 = inv_s[kb * 4 + 3];
  {
    const int d0 = (w * 2 + 0) * 16 + frow;
    abt[d0 * 20 + kb * 4 + 0] = f2bf(acc0[0] * i0);
    abt[d0 * 20 + kb * 4 + 1] = f2bf(acc0[1] * i1);
    abt[d0 * 20 + kb * 4 + 2] = f2bf(acc0[2] * i2);
    abt[d0 * 20 + kb * 4 + 3] = f2bf(acc0[3] * i3);
    const int d1 = (w * 2 + 1) * 16 + frow;
    abt[d1 * 20 + kb * 4 + 0] = f2bf(acc1[0] * i0);
    abt[d1 * 20 + kb * 4 + 1] = f2bf(acc1[1] * i1);
    abt[d1 * 20 + kb * 4 + 2] = f2bf(acc1[2] * i2);
    abt[d1 * 20 + kb * 4 + 3] = f2bf(acc1[3] * i3);
  }
  __syncthreads();
  const int d = t >> 1, h = t & 1;
  short8 ov;
#pragma unroll
  for (int j = 0; j < 8; ++j)
    ((unsigned short*)&ov)[j] = abt[d * 20 + h * 8 + j];
  *(short8*)(AbT + ((size_t)b * DD + d) * LQ + q0 + h * 8) = ov;
}

// ---------------------------------------------------------------------------
// K_out (MFMA): c2q = Sbar@xq, q2c = Sbar@A; fused concat epilogue.
// block = (b, 64-c tile), 4 waves; wave owns d-range w*32 (2 n-tiles).
// ---------------------------------------------------------------------------
__global__ __launch_bounds__(256) void k_out(
    const float* __restrict__ xc, const float* __restrict__ sbar,
    const unsigned short* __restrict__ xqT, const unsigned short* __restrict__ AbT,
    float* __restrict__ out) {
  __shared__ __align__(16) unsigned short sbs[64 * 136];  // 17408 B
  const int b = blockIdx.x >> 4;
  const int c0 = (blockIdx.x & 15) << 6;
  const int t = threadIdx.x;
  const int w = t >> 6, lane = t & 63;
  const int frow = lane & 15, kb = lane >> 4;

  const float* sb_blk = sbar + ((size_t)b * LC + c0) * LQ;
#pragma unroll
  for (int i = 0; i < 8; ++i) {
    const int id = t + (i << 8);
    const int row = id >> 5, u = id & 31;
    const float4 v = *(const float4*)(sb_blk + (size_t)row * LQ + (u << 2));
    ushort4v pk;
    pk[0] = f2bf(v.x); pk[1] = f2bf(v.y); pk[2] = f2bf(v.z); pk[3] = f2bf(v.w);
    *(ushort4v*)(sbs + row * 136 + (u << 2)) = pk;
  }

  const unsigned short* xqT_b = xqT + (size_t)b * DD * LQ;
  const unsigned short* AbT_b = AbT + (size_t)b * DD * LQ;
  short8 bq[2][4], ba[2][4];
#pragma unroll
  for (int nt = 0; nt < 2; ++nt) {
    const int d = (w << 5) + (nt << 4) + frow;
#pragma unroll
    for (int ks = 0; ks < 4; ++ks) {
      bq[nt][ks] = *(const short8*)(xqT_b + (size_t)d * LQ + ks * 32 + kb * 8);
      ba[nt][ks] = *(const short8*)(AbT_b + (size_t)d * LQ + ks * 32 + kb * 8);
    }
  }
  __syncthreads();

  floatx4 accq[4][2], acca[4][2];
#pragma unroll
  for (int mt = 0; mt < 4; ++mt)
#pragma unroll
    for (int nt = 0; nt < 2; ++nt) {
      accq[mt][nt] = (floatx4){0.f, 0.f, 0.f, 0.f};
      acca[mt][nt] = (floatx4){0.f, 0.f, 0.f, 0.f};
    }
#pragma unroll
  for (int mt = 0; mt < 4; ++mt) {
#pragma unroll
    for (int ks = 0; ks < 4; ++ks) {
      const short8 af =
          *(const short8*)(sbs + ((mt << 4) + frow) * 136 + ks * 32 + kb * 8);
#pragma unroll
      for (int nt = 0; nt < 2; ++nt) {
        accq[mt][nt] =
            __builtin_amdgcn_mfma_f32_16x16x32_bf16(af, bq[nt][ks], accq[mt][nt], 0, 0, 0);
        acca[mt][nt] =
            __builtin_amdgcn_mfma_f32_16x16x32_bf16(af, ba[nt][ks], acca[mt][nt], 0, 0, 0);
      }
    }
  }

  float* out_b = out + ((size_t)b * LC + c0) * (4 * DD);
  const float* xc_blk = xc + ((size_t)b * LC + c0) * DD;
#pragma unroll
  for (int mt = 0; mt < 4; ++mt) {
#pragma unroll
    for (int nt = 0; nt < 2; ++nt) {
      const int d = (w << 5) + (nt << 4) + frow;
#pragma unroll
      for (int reg = 0; reg < 4; ++reg) {
        const int c = (mt << 4) + (kb << 2) + reg;
        const float xv = xc_blk[(size_t)c * DD + d];
        float* o = out_b + (size_t)c * (4 * DD);
        const float cq = accq[mt][nt][reg];
        const float qc = acca[mt][nt][reg];
        o[d] = xv;
        o[DD + d] = cq;
        o[2 * DD + d] = xv * cq;
        o[3 * DD + d] = xv * qc;
      }
    }
  }
}

extern "C" void kernel_launch(void* const* d_in, const int* in_sizes, int n_in,
                              void* d_out, int out_size, void* d_ws, size_t ws_size,
                              hipStream_t stream) {
  const float* xc = (const float*)d_in[0];
  const float* xq = (const float*)d_in[1];
  const float* W0 = (const float*)d_in[2];
  const float* W1 = (const float*)d_in[3];
  const float* W2 = (const float*)d_in[4];
  const int* clen = (const int*)d_in[5];
  const int* qlen = (const int*)d_in[6];

  float* out = (float*)d_out;
  float* out_sbar = out + (size_t)NB * LC * 4 * DD;
  float* out_st = out_sbar + (size_t)NB * LC * LQ;

  float* a_cont = (float*)d_ws;                       // 64K f32
  float* a_ques = a_cont + NB * LC;                   // 8K f32
  unsigned short* xcb = (unsigned short*)(a_ques + NB * LQ);  // 8.4M u16
  unsigned short* xcT = xcb + (size_t)NB * LC * DD;           // 8.4M u16
  unsigned short* xqwb = xcT + (size_t)NB * LC * DD;          // 1M u16
  unsigned short* xqT = xqwb + (size_t)NB * LQ * DD;          // 1M u16
  unsigned short* AbT = xqT + (size_t)NB * LQ * DD;           // 1M u16

  k_pre_c<<<NB * 16, 256, 0, stream>>>(xc, W0, xcb, xcT, a_cont);
  k_pre_q<<<NB, 256, 0, stream>>>(xq, W1, W2, xqwb, xqT, a_ques);
  k_score<<<NB * 8, 512, 0, stream>>>(xcb, xqwb, a_cont, a_ques, qlen,
                                      out_sbar, out_st);
  k_fuse<<<NB * 8, 256, 0, stream>>>(out_st, xcT, clen, AbT);
  k_out<<<NB * 16, 256, 0, stream>>>(xc, out_sbar, xqT, AbT, out);
}